// Round 1
// baseline (368.817 us; speedup 1.0000x reference)
//
#include <hip/hip_runtime.h>

#define E_DIM 1024
#define D_DIM 128
#define T_DIM 4096
#define B_DIM 4

typedef unsigned short u16;
typedef u16 u16x8 __attribute__((ext_vector_type(8)));
typedef __bf16 bf16x8 __attribute__((ext_vector_type(8)));
typedef float f32x4 __attribute__((ext_vector_type(4)));

__device__ __forceinline__ u16 cvt_bf16(float f) {
    unsigned u = __float_as_uint(f);
    u += 0x7FFF + ((u >> 16) & 1);   // RNE
    return (u16)(u >> 16);
}

__device__ __forceinline__ f32x4 mfma16(u16x8 a, u16x8 b, f32x4 c) {
    return __builtin_amdgcn_mfma_f32_16x16x32_bf16(
        __builtin_bit_cast(bf16x8, a), __builtin_bit_cast(bf16x8, b), c, 0, 0, 0);
}

// ---------- prep: transpose weights to [out][in], cast to bf16 ----------
__global__ void prep_kernel(const float* __restrict__ Wk, const float* __restrict__ Wq,
                            const float* __restrict__ Wv, const float* __restrict__ Wp,
                            u16* __restrict__ Wqt, u16* __restrict__ Wkt,
                            u16* __restrict__ Wvt, u16* __restrict__ Wpt) {
    int tid = blockIdx.x * 256 + threadIdx.x;
    const int WT = 128 * 1024;
    if (tid < 3 * WT) {
        int w = tid / WT;
        int r = tid - w * WT;
        int n = r >> 10, k = r & 1023;
        const float* W = (w == 0) ? Wq : (w == 1) ? Wk : Wv;
        u16* Wt = (w == 0) ? Wqt : (w == 1) ? Wkt : Wvt;
        Wt[r] = cvt_bf16(W[k * 128 + n]);
    } else {
        int r = tid - 3 * WT;
        if (r < 128 * 128) {
            int n = r >> 7, k = r & 127;
            Wpt[r] = cvt_bf16(Wp[k * 128 + n]);
        }
    }
}

// ---------- fused QKV projection: [16384,1024] x [1024,384] -> bf16 q,k,v ----------
__global__ __launch_bounds__(256) void qkv_kernel(
        const float* __restrict__ x,
        const u16* __restrict__ Wqt, const u16* __restrict__ Wkt, const u16* __restrict__ Wvt,
        u16* __restrict__ qb, u16* __restrict__ kb, u16* __restrict__ vb) {
    __shared__ u16 Xs[64][40];        // 64 rows x 32 k, pad->40 (2-way bank alias only)
    __shared__ u16 Ws[3][128][40];    // [weight][n][k]

    const int t = threadIdx.x;
    const int w = t >> 6;
    const int lane = t & 63;
    const int lr = lane & 15;
    const int lg = lane >> 4;
    const int r0 = blockIdx.x * 64;

    f32x4 acc[24];
    #pragma unroll
    for (int i = 0; i < 24; ++i) acc[i] = f32x4{0.f, 0.f, 0.f, 0.f};

    const int xrow = t >> 2;          // 0..63
    const int xseg = t & 3;           // 0..3, 8 floats each
    const int wn   = t >> 1;          // 0..127
    const int wh   = (t & 1) * 16;    // 0 or 16

    for (int k0 = 0; k0 < E_DIM; k0 += 32) {
        // stage x tile (fp32 -> bf16)
        const float* xp = x + (size_t)(r0 + xrow) * E_DIM + k0 + xseg * 8;
        float4 a0 = *(const float4*)xp;
        float4 a1 = *(const float4*)(xp + 4);
        u16x8 xv;
        xv[0] = cvt_bf16(a0.x); xv[1] = cvt_bf16(a0.y);
        xv[2] = cvt_bf16(a0.z); xv[3] = cvt_bf16(a0.w);
        xv[4] = cvt_bf16(a1.x); xv[5] = cvt_bf16(a1.y);
        xv[6] = cvt_bf16(a1.z); xv[7] = cvt_bf16(a1.w);
        *(u16x8*)&Xs[xrow][xseg * 8] = xv;
        // stage W tiles (already transposed bf16: Wt[n][k])
        #pragma unroll
        for (int j = 0; j < 3; ++j) {
            const u16* Wt = (j == 0) ? Wqt : (j == 1) ? Wkt : Wvt;
            const u16* wp = Wt + (size_t)wn * E_DIM + k0 + wh;
            *(u16x8*)&Ws[j][wn][wh]     = *(const u16x8*)wp;
            *(u16x8*)&Ws[j][wn][wh + 8] = *(const u16x8*)(wp + 8);
        }
        __syncthreads();

        u16x8 av = *(u16x8*)&Xs[16 * w + lr][lg * 8];
        #pragma unroll
        for (int nt = 0; nt < 24; ++nt) {
            int j = nt >> 3;
            int n = (nt & 7) * 16 + lr;
            u16x8 bv = *(u16x8*)&Ws[j][n][lg * 8];
            acc[nt] = mfma16(av, bv, acc[nt]);
        }
        __syncthreads();
    }

    // epilogue: D layout col=lane&15, row=4*(lane>>4)+reg
    #pragma unroll
    for (int nt = 0; nt < 24; ++nt) {
        int j = nt >> 3;
        u16* outb = (j == 0) ? qb : (j == 1) ? kb : vb;
        int col = (nt & 7) * 16 + lr;
        #pragma unroll
        for (int reg = 0; reg < 4; ++reg) {
            int row = r0 + 16 * w + 4 * lg + reg;
            outb[(size_t)row * D_DIM + col] = cvt_bf16(acc[nt][reg]);
        }
    }
}

// ---------- flash attention (causal) + fused output projection ----------
__global__ __launch_bounds__(256) void attn_kernel(
        const u16* __restrict__ qb, const u16* __restrict__ kb, const u16* __restrict__ vb,
        const u16* __restrict__ Wpt, float* __restrict__ out) {
    __shared__ u16 Qs[64][136];   // Q tile; reused as O tile in epilogue
    __shared__ u16 Ks[32][136];
    __shared__ u16 Vt[128][40];   // V transposed: Vt[d][s]
    __shared__ u16 Ps[4][16][40]; // per-wave P tile

    const int t = threadIdx.x;
    const int w = t >> 6;
    const int lane = t & 63;
    const int lr = lane & 15;
    const int lg = lane >> 4;
    const int q0 = blockIdx.x * 64;
    const int b = blockIdx.y;
    const size_t base = (size_t)b * T_DIM * D_DIM;

    // stage Q (64x128)
    {
        int row = t >> 2, seg = (t & 3) * 32;
        const u16* src = qb + base + (size_t)(q0 + row) * D_DIM + seg;
        #pragma unroll
        for (int i = 0; i < 4; ++i)
            *(u16x8*)&Qs[row][seg + i * 8] = *(const u16x8*)(src + i * 8);
    }
    __syncthreads();
    u16x8 qf[4];
    #pragma unroll
    for (int dk = 0; dk < 4; ++dk)
        qf[dk] = *(u16x8*)&Qs[16 * w + lr][dk * 32 + lg * 8];

    f32x4 oacc[8];
    #pragma unroll
    for (int i = 0; i < 8; ++i) oacc[i] = f32x4{0.f, 0.f, 0.f, 0.f};
    float m_run[4], l_run[4];
    #pragma unroll
    for (int r = 0; r < 4; ++r) { m_run[r] = -1e30f; l_run[r] = 0.f; }

    const float scale = 0.08838834764831845f;  // 1/sqrt(128)
    const int s_endt = q0 + 64;

    for (int s0 = 0; s0 < s_endt; s0 += 32) {
        // stage K (row-major) and V (transposed)
        {
            int row = t >> 3, seg = (t & 7) * 16;
            const u16* ksrc = kb + base + (size_t)(s0 + row) * D_DIM + seg;
            *(u16x8*)&Ks[row][seg]     = *(const u16x8*)ksrc;
            *(u16x8*)&Ks[row][seg + 8] = *(const u16x8*)(ksrc + 8);
            const u16* vsrc = vb + base + (size_t)(s0 + row) * D_DIM + seg;
            u16x8 v0 = *(const u16x8*)vsrc;
            u16x8 v1 = *(const u16x8*)(vsrc + 8);
            #pragma unroll
            for (int i = 0; i < 8; ++i) {
                Vt[seg + i][row]     = v0[i];
                Vt[seg + 8 + i][row] = v1[i];
            }
        }
        __syncthreads();

        // S = Q K^T  (A=Q, B=K row-major as Bs[n=s][k=d])
        f32x4 sacc[2];
        sacc[0] = f32x4{0.f, 0.f, 0.f, 0.f};
        sacc[1] = f32x4{0.f, 0.f, 0.f, 0.f};
        #pragma unroll
        for (int dk = 0; dk < 4; ++dk) {
            #pragma unroll
            for (int nt = 0; nt < 2; ++nt) {
                u16x8 bv = *(u16x8*)&Ks[nt * 16 + lr][dk * 32 + lg * 8];
                sacc[nt] = mfma16(qf[dk], bv, sacc[nt]);
            }
        }

        // scale + causal mask
        float s_val[2][4];
        const bool need_mask = (s0 + 31 > q0);
        #pragma unroll
        for (int nt = 0; nt < 2; ++nt) {
            int scol = s0 + nt * 16 + lr;
            #pragma unroll
            for (int r = 0; r < 4; ++r) {
                int qrow = q0 + 16 * w + 4 * lg + r;
                float sv = sacc[nt][r] * scale;
                if (need_mask && scol > qrow) sv = -1e30f;
                s_val[nt][r] = sv;
            }
        }

        // online softmax (rows live on 16-lane groups)
        float p[2][4], rsc[4];
        #pragma unroll
        for (int r = 0; r < 4; ++r) {
            float tmax = fmaxf(s_val[0][r], s_val[1][r]);
            #pragma unroll
            for (int off = 1; off < 16; off <<= 1)
                tmax = fmaxf(tmax, __shfl_xor(tmax, off));
            float m_new = fmaxf(m_run[r], tmax);
            rsc[r] = __expf(m_run[r] - m_new);
            p[0][r] = __expf(s_val[0][r] - m_new);
            p[1][r] = __expf(s_val[1][r] - m_new);
            float tsum = p[0][r] + p[1][r];
            #pragma unroll
            for (int off = 1; off < 16; off <<= 1)
                tsum += __shfl_xor(tsum, off);
            l_run[r] = l_run[r] * rsc[r] + tsum;
            m_run[r] = m_new;
        }
        #pragma unroll
        for (int nt = 0; nt < 8; ++nt)
            #pragma unroll
            for (int r = 0; r < 4; ++r)
                oacc[nt][r] *= rsc[r];

        // P -> LDS (per-wave private)
        #pragma unroll
        for (int nt = 0; nt < 2; ++nt)
            #pragma unroll
            for (int r = 0; r < 4; ++r)
                Ps[w][4 * lg + r][nt * 16 + lr] = cvt_bf16(p[nt][r]);

        // O += P V   (A=P[q][s], B=Vt[n=d][k=s])
        u16x8 av = *(u16x8*)&Ps[w][lr][lg * 8];
        #pragma unroll
        for (int nt = 0; nt < 8; ++nt) {
            u16x8 bv = *(u16x8*)&Vt[nt * 16 + lr][lg * 8];
            oacc[nt] = mfma16(av, bv, oacc[nt]);
        }
        __syncthreads();
    }

    // normalize, O -> LDS (reuse Qs; intra-wave rows only)
    #pragma unroll
    for (int r = 0; r < 4; ++r) l_run[r] = 1.f / l_run[r];
    #pragma unroll
    for (int nt = 0; nt < 8; ++nt)
        #pragma unroll
        for (int r = 0; r < 4; ++r)
            Qs[16 * w + 4 * lg + r][nt * 16 + lr] = cvt_bf16(oacc[nt][r] * l_run[r]);

    // Y = O @ Wp  (B from global Wpt[n][k], L2-resident)
    u16x8 af[4];
    #pragma unroll
    for (int dk = 0; dk < 4; ++dk)
        af[dk] = *(u16x8*)&Qs[16 * w + lr][dk * 32 + lg * 8];
    float* op = out + base;
    #pragma unroll
    for (int nt = 0; nt < 8; ++nt) {
        f32x4 y = f32x4{0.f, 0.f, 0.f, 0.f};
        #pragma unroll
        for (int dk = 0; dk < 4; ++dk) {
            u16x8 bv = *(const u16x8*)&Wpt[(size_t)(nt * 16 + lr) * D_DIM + dk * 32 + lg * 8];
            y = mfma16(af[dk], bv, y);
        }
        int col = nt * 16 + lr;
        #pragma unroll
        for (int r = 0; r < 4; ++r) {
            int row = q0 + 16 * w + 4 * lg + r;
            op[(size_t)row * D_DIM + col] = y[r];
        }
    }
}

extern "C" void kernel_launch(void* const* d_in, const int* in_sizes, int n_in,
                              void* d_out, int out_size, void* d_ws, size_t ws_size,
                              hipStream_t stream) {
    const float* x  = (const float*)d_in[0];
    const float* Wk = (const float*)d_in[1];
    const float* Wq = (const float*)d_in[2];
    const float* Wv = (const float*)d_in[3];
    const float* Wp = (const float*)d_in[4];
    float* out = (float*)d_out;

    char* ws = (char*)d_ws;
    u16* qb  = (u16*)(ws);                         // 4 MB
    u16* kb  = (u16*)(ws + 4194304);               // 4 MB
    u16* vb  = (u16*)(ws + 8388608);               // 4 MB
    u16* Wqt = (u16*)(ws + 12582912);              // 256 KB
    u16* Wkt = (u16*)(ws + 12582912 + 262144);
    u16* Wvt = (u16*)(ws + 12582912 + 524288);
    u16* Wpt = (u16*)(ws + 12582912 + 786432);     // 32 KB

    prep_kernel<<<1600, 256, 0, stream>>>(Wk, Wq, Wv, Wp, Wqt, Wkt, Wvt, Wpt);
    qkv_kernel<<<256, 256, 0, stream>>>(x, Wqt, Wkt, Wvt, qb, kb, vb);
    attn_kernel<<<dim3(64, 4), 256, 0, stream>>>(qb, kb, vb, Wpt, out);
}

// Round 3
// 152.294 us; speedup vs baseline: 2.4217x; 2.4217x over previous
//
#include <hip/hip_runtime.h>

#define E_DIM 1024
#define D_DIM 128
#define T_DIM 4096

typedef unsigned short u16;
typedef u16 u16x8 __attribute__((ext_vector_type(8)));
typedef u16 u16x4 __attribute__((ext_vector_type(4)));
typedef __bf16 bf16x8 __attribute__((ext_vector_type(8)));
typedef float f32x4 __attribute__((ext_vector_type(4)));

__device__ __forceinline__ u16 cvt_bf16(float f) {
    unsigned u = __float_as_uint(f);
    u += 0x7FFF + ((u >> 16) & 1);   // RNE
    return (u16)(u >> 16);
}

__device__ __forceinline__ f32x4 mfma16(u16x8 a, u16x8 b, f32x4 c) {
    return __builtin_amdgcn_mfma_f32_16x16x32_bf16(
        __builtin_bit_cast(bf16x8, a), __builtin_bit_cast(bf16x8, b), c, 0, 0, 0);
}

// ---------- prep: transpose weights to [out][in], cast to bf16 ----------
__global__ void prep_kernel(const float* __restrict__ Wk, const float* __restrict__ Wq,
                            const float* __restrict__ Wv, const float* __restrict__ Wp,
                            u16* __restrict__ Wqt, u16* __restrict__ Wkt,
                            u16* __restrict__ Wvt, u16* __restrict__ Wpt) {
    int tid = blockIdx.x * 256 + threadIdx.x;
    const int WT = 128 * 1024;
    if (tid < 3 * WT) {
        int w = tid / WT;
        int r = tid - w * WT;
        int n = r >> 10, k = r & 1023;
        const float* W = (w == 0) ? Wq : (w == 1) ? Wk : Wv;
        u16* Wt = (w == 0) ? Wqt : (w == 1) ? Wkt : Wvt;
        Wt[r] = cvt_bf16(W[k * 128 + n]);
    } else {
        int r = tid - 3 * WT;
        if (r < 128 * 128) {
            int n = r >> 7, k = r & 127;
            Wpt[r] = cvt_bf16(Wp[k * 128 + n]);
        }
    }
}

// ---------- fused QKV projection: x[16384,1024] -> q,k row-major bf16 + v transposed ----------
__global__ __launch_bounds__(256) void qkv_kernel(
        const float* __restrict__ x,
        const u16* __restrict__ Wqt, const u16* __restrict__ Wkt, const u16* __restrict__ Wvt,
        u16* __restrict__ qb, u16* __restrict__ kb, u16* __restrict__ vT) {
    __shared__ u16 Xs[64][40];
    __shared__ u16 Ws[3][128][40];

    const int t = threadIdx.x;
    const int w = t >> 6;
    const int lane = t & 63;
    const int lr = lane & 15;
    const int lg = lane >> 4;
    const int r0 = blockIdx.x * 64;

    f32x4 acc[24];
    #pragma unroll
    for (int i = 0; i < 24; ++i) acc[i] = f32x4{0.f, 0.f, 0.f, 0.f};

    const int xrow = t >> 2;
    const int xseg = t & 3;
    const int wn   = t >> 1;
    const int wh   = (t & 1) * 16;

    const float* xp0 = x + (size_t)(r0 + xrow) * E_DIM + xseg * 8;

    // preload k0=0 into regs
    float4 a0 = *(const float4*)(xp0);
    float4 a1 = *(const float4*)(xp0 + 4);
    u16x8 wr[3][2];
    {
        const u16* w0 = Wqt + (size_t)wn * E_DIM + wh;
        const u16* w1 = Wkt + (size_t)wn * E_DIM + wh;
        const u16* w2 = Wvt + (size_t)wn * E_DIM + wh;
        wr[0][0] = *(const u16x8*)w0; wr[0][1] = *(const u16x8*)(w0 + 8);
        wr[1][0] = *(const u16x8*)w1; wr[1][1] = *(const u16x8*)(w1 + 8);
        wr[2][0] = *(const u16x8*)w2; wr[2][1] = *(const u16x8*)(w2 + 8);
    }

    for (int k0 = 0; k0 < E_DIM; k0 += 32) {
        // write staged regs to LDS
        u16x8 xv;
        xv[0] = cvt_bf16(a0.x); xv[1] = cvt_bf16(a0.y);
        xv[2] = cvt_bf16(a0.z); xv[3] = cvt_bf16(a0.w);
        xv[4] = cvt_bf16(a1.x); xv[5] = cvt_bf16(a1.y);
        xv[6] = cvt_bf16(a1.z); xv[7] = cvt_bf16(a1.w);
        *(u16x8*)&Xs[xrow][xseg * 8] = xv;
        #pragma unroll
        for (int j = 0; j < 3; ++j) {
            *(u16x8*)&Ws[j][wn][wh]     = wr[j][0];
            *(u16x8*)&Ws[j][wn][wh + 8] = wr[j][1];
        }
        __syncthreads();

        // prefetch next tile
        if (k0 + 32 < E_DIM) {
            const float* xp = xp0 + k0 + 32;
            a0 = *(const float4*)(xp);
            a1 = *(const float4*)(xp + 4);
            const u16* w0 = Wqt + (size_t)wn * E_DIM + k0 + 32 + wh;
            const u16* w1 = Wkt + (size_t)wn * E_DIM + k0 + 32 + wh;
            const u16* w2 = Wvt + (size_t)wn * E_DIM + k0 + 32 + wh;
            wr[0][0] = *(const u16x8*)w0; wr[0][1] = *(const u16x8*)(w0 + 8);
            wr[1][0] = *(const u16x8*)w1; wr[1][1] = *(const u16x8*)(w1 + 8);
            wr[2][0] = *(const u16x8*)w2; wr[2][1] = *(const u16x8*)(w2 + 8);
        }

        u16x8 av = *(u16x8*)&Xs[16 * w + lr][lg * 8];
        #pragma unroll
        for (int nt = 0; nt < 24; ++nt) {
            int j = nt >> 3;
            int n = (nt & 7) * 16 + lr;
            u16x8 bv = *(u16x8*)&Ws[j][n][lg * 8];
            acc[nt] = mfma16(av, bv, acc[nt]);
        }
        __syncthreads();
    }

    // epilogue: D layout col=lane&15, row=4*(lane>>4)+reg
    const int row0 = r0 + 16 * w + 4 * lg;
    const int bb = row0 >> 12;
    const int tt = row0 & 4095;
    #pragma unroll
    for (int nt = 0; nt < 24; ++nt) {
        int j = nt >> 3;
        int col = (nt & 7) * 16 + lr;
        if (j < 2) {
            u16* outb = (j == 0) ? qb : kb;
            #pragma unroll
            for (int reg = 0; reg < 4; ++reg)
                outb[(size_t)(row0 + reg) * D_DIM + col] = cvt_bf16(acc[nt][reg]);
        } else {
            u16x4 pv;
            #pragma unroll
            for (int reg = 0; reg < 4; ++reg) pv[reg] = cvt_bf16(acc[nt][reg]);
            *(u16x4*)&vT[((size_t)(bb * 128 + col)) * T_DIM + tt] = pv;
        }
    }
}

// ---------- flash attention (causal), kv-chunked, writes unnormalized partials ----------
__global__ __launch_bounds__(256) void attn_kernel(
        const u16* __restrict__ qb, const u16* __restrict__ kb, const u16* __restrict__ vT,
        float* __restrict__ Opart, float* __restrict__ ml, int CHK, int MAXC) {
    const int i = blockIdx.x;
    const int b = blockIdx.y;
    const int c = blockIdx.z;
    const int q0 = i * 64;
    const int kvlen = q0 + 64;
    const int kv_beg = c * CHK;
    if (kv_beg >= kvlen) return;
    const int kv_end = min(kv_beg + CHK, kvlen);
    const int slot = (b * 64 + i) * MAXC + c;

    __shared__ __align__(16) char smem[45056];
    u16 (*Ks)[136] = reinterpret_cast<u16(*)[136]>(smem);            // 64x136 = 17408B
    u16 (*Vt)[72]  = reinterpret_cast<u16(*)[72]>(smem + 17408);     // 128x72 = 18432B
    u16 (*Ps)[72]  = reinterpret_cast<u16(*)[72]>(smem + 35840);     // 64x72  =  9216B

    const int t = threadIdx.x;
    const int w = t >> 6;
    const int lane = t & 63;
    const int lr = lane & 15;
    const int lg = lane >> 4;
    const size_t base = (size_t)b * T_DIM * D_DIM;

    // Q fragments direct from global (L2-resident)
    u16x8 qf[4];
    {
        const u16* qp = qb + base + (size_t)(q0 + 16 * w + lr) * D_DIM + lg * 8;
        #pragma unroll
        for (int dk = 0; dk < 4; ++dk) qf[dk] = *(const u16x8*)(qp + dk * 32);
    }

    const int kr = t >> 2, kc = (t & 3) * 32;
    const int vd = t >> 1, vc = (t & 1) * 32;
    const u16* kpb = kb + base;
    const u16* vpb = vT + (size_t)b * D_DIM * T_DIM;

    u16x8 kreg[4], vreg[4];
    #define LOAD_TILE(S0) do {                                             \
        const u16* kp = kpb + (size_t)((S0) + kr) * D_DIM + kc;            \
        const u16* vp = vpb + (size_t)vd * T_DIM + (S0) + vc;              \
        kreg[0] = *(const u16x8*)(kp);      kreg[1] = *(const u16x8*)(kp + 8);  \
        kreg[2] = *(const u16x8*)(kp + 16); kreg[3] = *(const u16x8*)(kp + 24); \
        vreg[0] = *(const u16x8*)(vp);      vreg[1] = *(const u16x8*)(vp + 8);  \
        vreg[2] = *(const u16x8*)(vp + 16); vreg[3] = *(const u16x8*)(vp + 24); \
    } while (0)

    f32x4 oacc[8];
    #pragma unroll
    for (int n = 0; n < 8; ++n) oacc[n] = f32x4{0.f, 0.f, 0.f, 0.f};
    float m_run[4], l_run[4];
    #pragma unroll
    for (int r = 0; r < 4; ++r) { m_run[r] = -1e30f; l_run[r] = 0.f; }
    const float scale = 0.08838834764831845f;  // 1/sqrt(128)

    LOAD_TILE(kv_beg);
    for (int s0 = kv_beg; s0 < kv_end; s0 += 64) {
        // drain staged regs into LDS
        #pragma unroll
        for (int j = 0; j < 4; ++j) *(u16x8*)&Ks[kr][kc + j * 8] = kreg[j];
        #pragma unroll
        for (int j = 0; j < 4; ++j) *(u16x8*)&Vt[vd][vc + j * 8] = vreg[j];
        __syncthreads();
        if (s0 + 64 < kv_end) LOAD_TILE(s0 + 64);

        // S = Q K^T
        f32x4 sacc[4];
        #pragma unroll
        for (int n = 0; n < 4; ++n) sacc[n] = f32x4{0.f, 0.f, 0.f, 0.f};
        #pragma unroll
        for (int dk = 0; dk < 4; ++dk) {
            #pragma unroll
            for (int nt = 0; nt < 4; ++nt) {
                u16x8 bv = *(u16x8*)&Ks[nt * 16 + lr][dk * 32 + lg * 8];
                sacc[nt] = mfma16(qf[dk], bv, sacc[nt]);
            }
        }

        float sv[4][4];
        const bool need_mask = (s0 + 63 > q0);
        #pragma unroll
        for (int nt = 0; nt < 4; ++nt) {
            int scol = s0 + nt * 16 + lr;
            #pragma unroll
            for (int r = 0; r < 4; ++r) {
                float v = sacc[nt][r] * scale;
                if (need_mask && scol > q0 + 16 * w + 4 * lg + r) v = -1e30f;
                sv[nt][r] = v;
            }
        }

        float p[4][4], rsc[4];
        #pragma unroll
        for (int r = 0; r < 4; ++r) {
            float tmax = fmaxf(fmaxf(sv[0][r], sv[1][r]), fmaxf(sv[2][r], sv[3][r]));
            #pragma unroll
            for (int off = 1; off < 16; off <<= 1)
                tmax = fmaxf(tmax, __shfl_xor(tmax, off));
            float m_new = fmaxf(m_run[r], tmax);
            rsc[r] = __expf(m_run[r] - m_new);
            float tsum = 0.f;
            #pragma unroll
            for (int nt = 0; nt < 4; ++nt) {
                p[nt][r] = __expf(sv[nt][r] - m_new);
                tsum += p[nt][r];
            }
            #pragma unroll
            for (int off = 1; off < 16; off <<= 1)
                tsum += __shfl_xor(tsum, off);
            l_run[r] = l_run[r] * rsc[r] + tsum;
            m_run[r] = m_new;
        }
        #pragma unroll
        for (int nt = 0; nt < 8; ++nt)
            #pragma unroll
            for (int r = 0; r < 4; ++r) oacc[nt][r] *= rsc[r];

        // P -> LDS (wave-private)
        #pragma unroll
        for (int nt = 0; nt < 4; ++nt)
            #pragma unroll
            for (int r = 0; r < 4; ++r)
                Ps[w * 16 + 4 * lg + r][nt * 16 + lr] = cvt_bf16(p[nt][r]);

        // O += P V
        u16x8 av0 = *(u16x8*)&Ps[w * 16 + lr][lg * 8];
        u16x8 av1 = *(u16x8*)&Ps[w * 16 + lr][32 + lg * 8];
        #pragma unroll
        for (int nt = 0; nt < 8; ++nt) {
            u16x8 bv0 = *(u16x8*)&Vt[nt * 16 + lr][lg * 8];
            oacc[nt] = mfma16(av0, bv0, oacc[nt]);
            u16x8 bv1 = *(u16x8*)&Vt[nt * 16 + lr][32 + lg * 8];
            oacc[nt] = mfma16(av1, bv1, oacc[nt]);
        }
        __syncthreads();
    }
    #undef LOAD_TILE

    // m,l per row (uniform across the 16-lane group; lane lr==0 writes)
    if (lr == 0) {
        #pragma unroll
        for (int r = 0; r < 4; ++r) {
            int row = 16 * w + 4 * lg + r;
            ml[(size_t)(slot * 64 + row) * 2]     = m_run[r];
            ml[(size_t)(slot * 64 + row) * 2 + 1] = l_run[r];
        }
    }

    // unnormalized O -> LDS bounce (f32) -> coalesced global store
    float (*Of)[132] = reinterpret_cast<float(*)[132]>(smem);
    #pragma unroll
    for (int nt = 0; nt < 8; ++nt)
        #pragma unroll
        for (int r = 0; r < 4; ++r)
            Of[16 * w + 4 * lg + r][nt * 16 + lr] = oacc[nt][r];
    __syncthreads();
    float* op = Opart + (size_t)slot * (64 * 128);
    const int orow = t >> 2, oseg = (t & 3) * 32;
    #pragma unroll
    for (int j = 0; j < 8; ++j)
        *(float4*)(op + orow * 128 + oseg + j * 4) = *(float4*)&Of[orow][oseg + j * 4];
}

// ---------- combine partials + fused output projection ----------
__global__ __launch_bounds__(256) void combine_kernel(
        const float* __restrict__ Opart, const float* __restrict__ ml,
        const u16* __restrict__ Wpt, float* __restrict__ out, int CHK, int MAXC) {
    const int i = blockIdx.x;
    const int b = blockIdx.y;
    const int kvlen = (i + 1) * 64;
    const int NC = (kvlen + CHK - 1) / CHK;
    const int slot0 = (b * 64 + i) * MAXC;

    __shared__ u16 Os[64][136];
    const int t = threadIdx.x;
    const int row = t >> 2, seg = (t & 3) * 32;

    float mc[4], lc[4], wgt[4];
    float m_fin = -1e30f;
    #pragma unroll 4
    for (int c = 0; c < 4; ++c) {
        if (c < NC) {
            mc[c] = ml[(size_t)((slot0 + c) * 64 + row) * 2];
            lc[c] = ml[(size_t)((slot0 + c) * 64 + row) * 2 + 1];
            m_fin = fmaxf(m_fin, mc[c]);
        }
    }
    float l_fin = 0.f;
    #pragma unroll 4
    for (int c = 0; c < 4; ++c) {
        if (c < NC) {
            wgt[c] = __expf(mc[c] - m_fin);
            l_fin += lc[c] * wgt[c];
        }
    }
    const float inv = 1.f / l_fin;

    float acc[32];
    #pragma unroll
    for (int j = 0; j < 32; ++j) acc[j] = 0.f;
    #pragma unroll 4
    for (int c = 0; c < 4; ++c) {
        if (c < NC) {
            const float* op = Opart + (size_t)(slot0 + c) * 8192 + row * 128 + seg;
            #pragma unroll
            for (int j = 0; j < 8; ++j) {
                float4 v = *(const float4*)(op + j * 4);
                acc[j * 4]     += v.x * wgt[c];
                acc[j * 4 + 1] += v.y * wgt[c];
                acc[j * 4 + 2] += v.z * wgt[c];
                acc[j * 4 + 3] += v.w * wgt[c];
            }
        }
    }
    #pragma unroll
    for (int j = 0; j < 4; ++j) {
        u16x8 ov;
        #pragma unroll
        for (int e = 0; e < 8; ++e) ov[e] = cvt_bf16(acc[j * 8 + e] * inv);
        *(u16x8*)&Os[row][seg + j * 8] = ov;
    }
    __syncthreads();

    // Y = O @ Wp
    const int w = t >> 6;
    const int lane = t & 63;
    const int lr = lane & 15;
    const int lg = lane >> 4;
    u16x8 af[4];
    #pragma unroll
    for (int dk = 0; dk < 4; ++dk)
        af[dk] = *(u16x8*)&Os[16 * w + lr][dk * 32 + lg * 8];
    float* op = out + ((size_t)b * T_DIM + i * 64) * D_DIM;
    #pragma unroll
    for (int nt = 0; nt < 8; ++nt) {
        f32x4 y = f32x4{0.f, 0.f, 0.f, 0.f};
        #pragma unroll
        for (int dk = 0; dk < 4; ++dk) {
            u16x8 bv = *(const u16x8*)&Wpt[(size_t)(nt * 16 + lr) * D_DIM + dk * 32 + lg * 8];
            y = mfma16(af[dk], bv, y);
        }
        #pragma unroll
        for (int r = 0; r < 4; ++r)
            op[(size_t)(16 * w + 4 * lg + r) * D_DIM + nt * 16 + lr] = y[r];
    }
}

extern "C" void kernel_launch(void* const* d_in, const int* in_sizes, int n_in,
                              void* d_out, int out_size, void* d_ws, size_t ws_size,
                              hipStream_t stream) {
    const float* x  = (const float*)d_in[0];
    const float* Wk = (const float*)d_in[1];
    const float* Wq = (const float*)d_in[2];
    const float* Wv = (const float*)d_in[3];
    const float* Wp = (const float*)d_in[4];
    float* out = (float*)d_out;

    char* ws = (char*)d_ws;
    u16* qb  = (u16*)(ws);                          // 4 MB
    u16* kb  = (u16*)(ws + 4194304);                // 4 MB
    u16* vT  = (u16*)(ws + 8388608);                // 4 MB, [b][d][t]
    u16* Wqt = (u16*)(ws + 12582912);               // 256 KB
    u16* Wkt = (u16*)(ws + 12582912 + 262144);
    u16* Wvt = (u16*)(ws + 12582912 + 524288);
    u16* Wpt = (u16*)(ws + 12582912 + 786432);      // 32 KB
    float* ml    = (float*)(ws + 13631488);         // up to 512 KB
    float* Opart = (float*)(ws + 14155776);         // up to 32 MB

    const bool big = ws_size >= (size_t)48 * 1024 * 1024;
    const int CHK  = big ? 1024 : 4096;   // kv chunk size
    const int MAXC = big ? 4 : 1;         // max chunks per q-tile

    prep_kernel<<<1600, 256, 0, stream>>>(Wk, Wq, Wv, Wp, Wqt, Wkt, Wvt, Wpt);
    qkv_kernel<<<256, 256, 0, stream>>>(x, Wqt, Wkt, Wvt, qb, kb, vT);
    attn_kernel<<<dim3(64, 4, MAXC), 256, 0, stream>>>(qb, kb, vT, Opart, ml, CHK, MAXC);
    combine_kernel<<<dim3(64, 4), 256, 0, stream>>>(Opart, ml, Wpt, out, CHK, MAXC);
}